// Round 1
// baseline (24797.168 us; speedup 1.0000x reference)
//
#include <hip/hip_runtime.h>
#include <hip/hip_bf16.h>
#include <math.h>

// Problem constants
#define BB 32
#define SS 64
#define TT 32
#define EE 512
#define HH 1024
#define VV 32000
#define H2 2048   // 2H
#define G4 4096   // 4H

#define KT 64

// ---------------------------------------------------------------------------
// Generic skinny GEMM: C[32, N] = sum over up to 3 K-segments of A_seg @ W_seg
//   A_seg stored feature-major: A[(k_local)*32 + b]
//   ORIENT 0: W is KxN  -> W[(koff + k_local)*ld + n]
//   ORIENT 1: W is NxK  -> W[n*ld + koff + k_local]
// Output: partials out_part[(blockIdx.y*32 + b)*N + n]  (reduced later)
// Block: 256 threads; tile: 32 b x 128 n; K-tile KT=64.
// ---------------------------------------------------------------------------
template<int ORIENT>
__global__ __launch_bounds__(256, 2) void gemm_m32(
    const float* __restrict__ A0, const float* __restrict__ W0, int koff0, int ld0, int kend0,
    const float* __restrict__ A1, const float* __restrict__ W1, int koff1, int ld1, int kend1,
    const float* __restrict__ A2, const float* __restrict__ W2, int koff2, int ld2,
    int KS_chunk, int N, float* __restrict__ out_part)
{
    __shared__ float a_t[32][KT + 4];
    __shared__ float w_t[128][KT + 4];
    const int tid  = threadIdx.x;
    const int lane = tid & 63;
    const int wv   = tid >> 6;
    const int n0   = blockIdx.x * 128;
    const int kstart = blockIdx.y * KS_chunk;
    const int kstop  = kstart + KS_chunk;

    float accA[8], accB[8];
#pragma unroll
    for (int i = 0; i < 8; ++i) { accA[i] = 0.f; accB[i] = 0.f; }

    for (int k0 = kstart; k0 < kstop; k0 += KT) {
        const float *A, *W; int koff, ld, kbase;
        if (k0 < kend0)      { A = A0; W = W0; koff = koff0; ld = ld0; kbase = 0; }
        else if (k0 < kend1) { A = A1; W = W1; koff = koff1; ld = ld1; kbase = kend0; }
        else                 { A = A2; W = W2; koff = koff2; ld = ld2; kbase = kend1; }
        const int kl = k0 - kbase;

        // A tile: 32 x KT (b-fast global => coalesced 128B)
        for (int idx = tid; idx < 32 * KT; idx += 256) {
            int b = idx & 31, kk = idx >> 5;
            a_t[b][kk] = A[(size_t)(kl + kk) * 32 + b];
        }
        // W tile: 128 x KT
        if (ORIENT == 0) {
            for (int idx = tid; idx < 128 * KT; idx += 256) {
                int ni = idx & 127, kk = idx >> 7;
                w_t[ni][kk] = W[(size_t)(koff + kl + kk) * ld + n0 + ni];
            }
        } else {
            for (int idx = tid; idx < 128 * KT; idx += 256) {
                int kk = idx & (KT - 1), ni = idx >> 6;
                w_t[ni][kk] = W[(size_t)(n0 + ni) * ld + koff + kl + kk];
            }
        }
        __syncthreads();

#pragma unroll
        for (int kk = 0; kk < KT; kk += 4) {
            float4 wA = *(const float4*)&w_t[lane][kk];
            float4 wB = *(const float4*)&w_t[lane + 64][kk];
#pragma unroll
            for (int i = 0; i < 8; ++i) {
                int b = wv + i * 4;
                float4 av = *(const float4*)&a_t[b][kk];
                accA[i] += av.x * wA.x + av.y * wA.y + av.z * wA.z + av.w * wA.w;
                accB[i] += av.x * wB.x + av.y * wB.y + av.z * wB.z + av.w * wB.w;
            }
        }
        __syncthreads();
    }

    float* outp = out_part + (size_t)(blockIdx.y * 32) * N;
#pragma unroll
    for (int i = 0; i < 8; ++i) {
        int b = wv + i * 4;
        outp[(size_t)b * N + n0 + lane]      = accA[i];
        outp[(size_t)b * N + n0 + 64 + lane] = accB[i];
    }
}

// ---------------------------------------------------------------------------
// proj_key = encoder_hidden(2048x2048) @ Wk(2048x1024)  -> pk[2048][1024]
// 64x64 tile per block, 256 threads, 4x4 micro-tile.
// ---------------------------------------------------------------------------
__global__ __launch_bounds__(256, 2) void k_projkey(
    const float* __restrict__ enc, const float* __restrict__ Wk, float* __restrict__ pk)
{
    __shared__ float a_t[KT][68];  // [kk][m]
    __shared__ float w_t[KT][68];  // [kk][n]
    const int tid = threadIdx.x;
    const int m0 = blockIdx.y * 64, n0 = blockIdx.x * 64;
    const int tm = tid >> 4, tn = tid & 15;
    float acc[4][4];
#pragma unroll
    for (int r = 0; r < 4; ++r)
#pragma unroll
        for (int c = 0; c < 4; ++c) acc[r][c] = 0.f;

    for (int k0 = 0; k0 < H2; k0 += KT) {
        for (int idx = tid; idx < 64 * KT; idx += 256) {
            int kk = idx & 63, i = idx >> 6;
            a_t[kk][i] = enc[(size_t)(m0 + i) * H2 + k0 + kk];
        }
        for (int idx = tid; idx < 64 * KT; idx += 256) {
            int i = idx & 63, kk = idx >> 6;
            w_t[kk][i] = Wk[(size_t)(k0 + kk) * HH + n0 + i];
        }
        __syncthreads();
#pragma unroll
        for (int kk = 0; kk < KT; ++kk) {
            float4 av = *(const float4*)&a_t[kk][tm * 4];
            float4 wv4 = *(const float4*)&w_t[kk][tn * 4];
            acc[0][0] += av.x * wv4.x; acc[0][1] += av.x * wv4.y; acc[0][2] += av.x * wv4.z; acc[0][3] += av.x * wv4.w;
            acc[1][0] += av.y * wv4.x; acc[1][1] += av.y * wv4.y; acc[1][2] += av.y * wv4.z; acc[1][3] += av.y * wv4.w;
            acc[2][0] += av.z * wv4.x; acc[2][1] += av.z * wv4.y; acc[2][2] += av.z * wv4.z; acc[2][3] += av.z * wv4.w;
            acc[3][0] += av.w * wv4.x; acc[3][1] += av.w * wv4.y; acc[3][2] += av.w * wv4.z; acc[3][3] += av.w * wv4.w;
        }
        __syncthreads();
    }
#pragma unroll
    for (int r = 0; r < 4; ++r) {
        float4 st = make_float4(acc[r][0], acc[r][1], acc[r][2], acc[r][3]);
        *(float4*)&pk[(size_t)(m0 + tm * 4 + r) * HH + n0 + tn * 4] = st;
    }
}

// Transpose ef_h/ef_c [32][2048] -> [2048][32]
__global__ void k_tref(const float* __restrict__ efh, const float* __restrict__ efc,
                       float* __restrict__ efhT, float* __restrict__ efcT)
{
    int idx = blockIdx.x * 256 + threadIdx.x;   // 65536
    int k = idx & 2047, b = idx >> 11;
    efhT[k * 32 + b] = efh[b * H2 + k];
    efcT[k * 32 + b] = efc[b * H2 + k];
}

// Reduce init partials + bias, tanh -> h_T [H][B], c_nat [B][H]
__global__ void k_init2(const float* __restrict__ ihp, const float* __restrict__ icp,
                        const float* __restrict__ bbh, const float* __restrict__ bbc,
                        float* __restrict__ h_T, float* __restrict__ c_nat)
{
    int idx = blockIdx.x * 256 + threadIdx.x;   // 32768
    int j = idx & 1023, b = idx >> 10;
    float hv = ihp[b * HH + j] + ihp[(32 + b) * HH + j] + bbh[j];
    float cv = icp[b * HH + j] + icp[(32 + b) * HH + j] + bbc[j];
    h_T[j * 32 + b]  = tanhf(hv);
    c_nat[b * HH + j] = tanhf(cv);
}

// Fused: q-partials reduce -> energy scores -> masked softmax -> context; embed gather
__global__ __launch_bounds__(256) void k_attn(
    const float* __restrict__ qp, const float* __restrict__ pk, const float* __restrict__ ve,
    const int* __restrict__ slen, const float* __restrict__ enc,
    const int* __restrict__ trg, const float* __restrict__ emb,
    float* __restrict__ ctx_T, float* __restrict__ xe_T, int t)
{
    __shared__ float q_s[HH];
    __shared__ float v_s[HH];
    __shared__ float sc[SS];
    const int b = blockIdx.x, tid = threadIdx.x;
    const int lane = tid & 63, wv = tid >> 6;

    for (int j = tid; j < HH; j += 256) {
        float s = 0.f;
#pragma unroll
        for (int z = 0; z < 8; ++z) s += qp[(size_t)(z * 32 + b) * HH + j];
        q_s[j] = s;
        v_s[j] = ve[j];
    }
    __syncthreads();

    // scores: each wave handles 16 s values
    for (int si = 0; si < 16; ++si) {
        int s = wv * 16 + si;
        float p = 0.f;
#pragma unroll
        for (int ii = 0; ii < 16; ++ii) {
            int j = ii * 64 + lane;
            float x = q_s[j] + pk[(size_t)(b * SS + s) * HH + j];
            // fast tanh: 2/(1+e^-2x) - 1 (|x| bounded well below overflow)
            float th = 2.f / (1.f + __expf(-2.f * x)) - 1.f;
            p += th * v_s[j];
        }
#pragma unroll
        for (int m = 32; m; m >>= 1) p += __shfl_xor(p, m);
        if (lane == 0) sc[s] = p;
    }
    __syncthreads();

    // masked softmax over S=64 on wave 0
    if (tid < 64) {
        int len = slen[b];
        float x = (tid < len) ? sc[tid] : -1e9f;
        float mx = x;
#pragma unroll
        for (int m = 32; m; m >>= 1) mx = fmaxf(mx, __shfl_xor(mx, m));
        float e = __expf(x - mx);
        float ssum = e;
#pragma unroll
        for (int m = 32; m; m >>= 1) ssum += __shfl_xor(ssum, m);
        sc[tid] = e / ssum;
    }
    __syncthreads();

    // context[b][d] = sum_s alpha[s] * enc[b][s][d]   -> ctx_T [2H][B]
    for (int d = tid; d < H2; d += 256) {
        float acc = 0.f;
#pragma unroll 8
        for (int s = 0; s < SS; ++s) acc += sc[s] * enc[(size_t)(b * SS + s) * H2 + d];
        ctx_T[d * 32 + b] = acc;
    }
    // embedding gather -> xe_T [E][B]
    int y = trg[b * TT + t];
    for (int k = tid; k < EE; k += 256) xe_T[k * 32 + b] = emb[(size_t)y * EE + k];
}

// LSTM cell: reduce gates partials (+biases), update c (natural), h (transposed)
__global__ void k_lstm(const float* __restrict__ gp, const float* __restrict__ bi,
                       const float* __restrict__ bh, float* __restrict__ c_nat,
                       float* __restrict__ h_T, float* __restrict__ hout, float* __restrict__ cout)
{
    int idx = blockIdx.x * 256 + threadIdx.x;   // 32768
    int j = idx & 1023, b = idx >> 10;
    float ig = bi[j]        + bh[j];
    float fg = bi[HH + j]   + bh[HH + j];
    float gg = bi[2*HH + j] + bh[2*HH + j];
    float og = bi[3*HH + j] + bh[3*HH + j];
#pragma unroll
    for (int z = 0; z < 14; ++z) {
        const float* p = gp + (size_t)(z * 32 + b) * G4 + j;
        ig += p[0]; fg += p[HH]; gg += p[2*HH]; og += p[3*HH];
    }
    float c_old = c_nat[b * HH + j];
    float si = 1.f / (1.f + expf(-ig));
    float sf = 1.f / (1.f + expf(-fg));
    float so = 1.f / (1.f + expf(-og));
    float tg = tanhf(gg);
    float cn = sf * c_old + si * tg;
    float hn = so * tanhf(cn);
    c_nat[b * HH + j] = cn;
    h_T[j * 32 + b] = hn;
    if (hout) { hout[b * HH + j] = hn; cout[b * HH + j] = cn; }
}

// Reduce pre partials -> preT [H][B]
__global__ void k_pret(const float* __restrict__ pp, float* __restrict__ preT)
{
    int idx = blockIdx.x * 256 + threadIdx.x;   // 32768
    int j = idx & 1023, b = idx >> 10;
    float s = 0.f;
#pragma unroll
    for (int z = 0; z < 14; ++z) s += pp[(size_t)(z * 32 + b) * HH + j];
    preT[j * 32 + b] = s;
}

// Generator softmax: reduce 2 gen partials + bias, softmax over V, write out[b][v][t]
__global__ __launch_bounds__(256) void k_sm(const float* __restrict__ gp,
                                            const float* __restrict__ bg,
                                            float* __restrict__ out, int t)
{
    __shared__ float red[8];
    const int b = blockIdx.x, tid = threadIdx.x;
    const int lane = tid & 63, wv = tid >> 6;
    float mx = -1e30f, sm = 0.f;
    for (int v = tid; v < VV; v += 256) {
        float x = gp[(size_t)b * VV + v] + gp[(size_t)(32 + b) * VV + v] + bg[v];
        if (x > mx) { sm = sm * __expf(mx - x) + 1.f; mx = x; }
        else        { sm += __expf(x - mx); }
    }
#pragma unroll
    for (int m = 32; m; m >>= 1) {
        float om = __shfl_xor(mx, m), os = __shfl_xor(sm, m);
        float nm = fmaxf(mx, om);
        sm = sm * __expf(mx - nm) + os * __expf(om - nm);
        mx = nm;
    }
    if (lane == 0) { red[wv * 2] = mx; red[wv * 2 + 1] = sm; }
    __syncthreads();
    if (tid == 0) {
        float M = red[0], Ssum = red[1];
        for (int w = 1; w < 4; ++w) {
            float om = red[w * 2], os = red[w * 2 + 1];
            float nm = fmaxf(M, om);
            Ssum = Ssum * __expf(M - nm) + os * __expf(om - nm);
            M = nm;
        }
        red[0] = M; red[1] = 1.f / Ssum;
    }
    __syncthreads();
    float M = red[0], rS = red[1];
    for (int v = tid; v < VV; v += 256) {
        float x = gp[(size_t)b * VV + v] + gp[(size_t)(32 + b) * VV + v] + bg[v];
        out[((size_t)b * VV + v) * TT + t] = __expf(x - M) * rS;
    }
}

// ---------------------------------------------------------------------------
extern "C" void kernel_launch(void* const* d_in, const int* in_sizes, int n_in,
                              void* d_out, int out_size, void* d_ws, size_t ws_size,
                              hipStream_t stream)
{
    (void)in_sizes; (void)n_in; (void)out_size; (void)ws_size;
    const int*   trg  = (const int*)d_in[0];
    const int*   slen = (const int*)d_in[1];
    const float* enc  = (const float*)d_in[2];
    const float* efh  = (const float*)d_in[3];
    const float* efc  = (const float*)d_in[4];
    const float* emb  = (const float*)d_in[5];
    const float* Wk   = (const float*)d_in[6];
    const float* Wq   = (const float*)d_in[7];
    const float* ve   = (const float*)d_in[8];
    const float* Wbh  = (const float*)d_in[9];
    const float* bbh  = (const float*)d_in[10];
    const float* Wbc  = (const float*)d_in[11];
    const float* bbc  = (const float*)d_in[12];
    const float* Wih  = (const float*)d_in[13];
    const float* Whh  = (const float*)d_in[14];
    const float* bih  = (const float*)d_in[15];
    const float* bhh  = (const float*)d_in[16];
    const float* Wpre = (const float*)d_in[17];
    const float* Wgen = (const float*)d_in[18];
    const float* bgen = (const float*)d_in[19];
    float* out = (float*)d_out;
    float* ws  = (float*)d_ws;

    // workspace layout (floats)
    float* pk      = ws;                       // 2097152
    float* h_T     = pk      + 2097152;        // 32768
    float* c_nat   = h_T     + 32768;          // 32768
    float* xe_T    = c_nat   + 32768;          // 16384
    float* ctx_T   = xe_T    + 16384;          // 65536
    float* preT    = ctx_T   + 65536;          // 32768
    float* qpart   = preT    + 32768;          // 8 *32*1024   = 262144
    float* gpart   = qpart   + 262144;         // 14*32*4096   = 1835008
    float* ppart   = gpart   + 1835008;        // 14*32*1024   = 458752
    float* genpart = ppart   + 458752;         // 2 *32*32000  = 2048000
    float* ihpart  = genpart + 2048000;        // 2 *32*1024   = 65536
    float* icpart  = ihpart  + 65536;          // 65536
    float* efhT    = icpart  + 65536;          // 65536
    float* efcT    = efhT    + 65536;          // 65536

    float* outHT = out + (size_t)BB * VV * TT;
    float* outCT = outHT + BB * HH;

    // ---- once-per-call setup ----
    k_tref<<<256, 256, 0, stream>>>(efh, efc, efhT, efcT);

    // h0/c0 init GEMMs: [32,2048] @ Wb{h,c}[2048,1024], KS=2 (chunk 1024)
    gemm_m32<0><<<dim3(8, 2), 256, 0, stream>>>(
        efhT, Wbh, 0, HH, H2,  efhT, Wbh, 0, HH, H2,  efhT, Wbh, 0, HH,
        1024, HH, ihpart);
    gemm_m32<0><<<dim3(8, 2), 256, 0, stream>>>(
        efcT, Wbc, 0, HH, H2,  efcT, Wbc, 0, HH, H2,  efcT, Wbc, 0, HH,
        1024, HH, icpart);
    k_init2<<<128, 256, 0, stream>>>(ihpart, icpart, bbh, bbc, h_T, c_nat);

    k_projkey<<<dim3(16, 32), 256, 0, stream>>>(enc, Wk, pk);

    // ---- decode steps ----
    for (int t = 0; t < TT; ++t) {
        // q = h @ Wq : K=1024, N=1024, KS=8 (chunk 128)
        gemm_m32<0><<<dim3(8, 8), 256, 0, stream>>>(
            h_T, Wq, 0, HH, HH,  h_T, Wq, 0, HH, HH,  h_T, Wq, 0, HH,
            128, HH, qpart);

        k_attn<<<32, 256, 0, stream>>>(qpart, pk, ve, slen, enc, trg, emb, ctx_T, xe_T, t);

        // gates = [xe|ctx] @ W_ih^T + h @ W_hh^T : K=3584, N=4096, KS=14 (chunk 256)
        gemm_m32<1><<<dim3(32, 14), 256, 0, stream>>>(
            xe_T,  Wih, 0,   2560, 512,
            ctx_T, Wih, 512, 2560, 2560,
            h_T,   Whh, 0,   HH,
            256, G4, gpart);

        k_lstm<<<128, 256, 0, stream>>>(gpart, bih, bhh, c_nat, h_T,
                                        (t == TT - 1) ? outHT : (float*)nullptr,
                                        (t == TT - 1) ? outCT : (float*)nullptr);

        // pre = [xe|h_new|ctx] @ W_pre : K=3584, N=1024, KS=14 (chunk 256)
        gemm_m32<0><<<dim3(8, 14), 256, 0, stream>>>(
            xe_T,  Wpre, 0,    HH, 512,
            h_T,   Wpre, 512,  HH, 1536,
            ctx_T, Wpre, 1536, HH,
            256, HH, ppart);

        k_pret<<<128, 256, 0, stream>>>(ppart, preT);

        // logits = pre @ W_gen : K=1024, N=32000, KS=2 (chunk 512)
        gemm_m32<0><<<dim3(250, 2), 256, 0, stream>>>(
            preT, Wgen, 0, VV, HH,  preT, Wgen, 0, VV, HH,  preT, Wgen, 0, VV,
            512, VV, genpart);

        k_sm<<<32, 256, 0, stream>>>(genpart, bgen, out, t);
    }
}